// Round 3
// baseline (519.287 us; speedup 1.0000x reference)
//
#include <hip/hip_runtime.h>
#include <hip/hip_bf16.h>
#include <stdint.h>

// Problem constants (B=8192, I=512, H=1024, D=8)
#define B_N 8192
#define I_N 512
#define H_N 1024

typedef __bf16 bf16x8 __attribute__((ext_vector_type(8)));
typedef float f32x4 __attribute__((ext_vector_type(4)));
typedef unsigned short u16;
typedef unsigned int u32;

__device__ inline void gld_lds16(const void* g, void* l) {
  __builtin_amdgcn_global_load_lds(
      (const __attribute__((address_space(1))) unsigned int*)g,
      (__attribute__((address_space(3))) unsigned int*)l,
      16, 0, 0);
}

__device__ inline u16 f2bf(float f) {
  __hip_bfloat16 h = __float2bfloat16(f);
  return __builtin_bit_cast(u16, h);
}

__device__ inline float bf2f(u16 b) {
  unsigned int u = ((unsigned int)b) << 16;
  return __builtin_bit_cast(float, u);
}

__device__ inline u32 pack2bf(float lo, float hi) {
  return (u32)f2bf(lo) | ((u32)f2bf(hi) << 16);
}

// ---------- fused f32 -> bf16 conversion for x, Wih, Whh (one launch) ----------
__global__ void cvt_all(const float* __restrict__ x, const float* __restrict__ wih,
                        const float* __restrict__ whh,
                        u16* __restrict__ xb, u16* __restrict__ wihb, u16* __restrict__ whhb) {
  int b = blockIdx.x;
  const float* src; u16* dst; int base;
  if (b < 2048)      { src = x;   dst = xb;   base = b; }
  else if (b < 2816) { src = wih; dst = wihb; base = b - 2048; }
  else               { src = whh; dst = whhb; base = b - 2816; }
  int i = (base * 256 + (int)threadIdx.x) * 8;
  float4 a0 = *(const float4*)(src + i);
  float4 a1 = *(const float4*)(src + i + 4);
  union { u16 u[8]; float4 v; } pk;
  pk.u[0] = f2bf(a0.x); pk.u[1] = f2bf(a0.y); pk.u[2] = f2bf(a0.z); pk.u[3] = f2bf(a0.w);
  pk.u[4] = f2bf(a1.x); pk.u[5] = f2bf(a1.y); pk.u[6] = f2bf(a1.z); pk.u[7] = f2bf(a1.w);
  *(float4*)(dst + i) = pk.v;
}

// ---------- hidden-state decay: hdec = exp(-relu(delta @ Wg^T + bg)) * h ----------
// 8 batch rows x 8 cols per thread: wg/delta stay in registers, ~10x less cache traffic
__global__ void decay_kernel(const float* __restrict__ h, const float* __restrict__ delta,
                             const float* __restrict__ wg, const float* __restrict__ bg,
                             u16* __restrict__ hdec) {
  int t = blockIdx.x * 256 + threadIdx.x;   // 131072 threads total
  int rg = t >> 7;          // batch group of 8 (0..1023)
  int jg = t & 127;         // col group of 8 (0..127)
  int r0 = rg * 8, j0 = jg * 8;
  float4 w[8][2];
#pragma unroll
  for (int j = 0; j < 8; ++j) {
    const float4* p = (const float4*)(wg + (size_t)(j0 + j) * 8);
    w[j][0] = p[0]; w[j][1] = p[1];
  }
  float4 bg0 = *(const float4*)(bg + j0);
  float4 bg1 = *(const float4*)(bg + j0 + 4);
  float bgl[8] = {bg0.x, bg0.y, bg0.z, bg0.w, bg1.x, bg1.y, bg1.z, bg1.w};
#pragma unroll
  for (int r = 0; r < 8; ++r) {
    const float4* dp = (const float4*)(delta + (size_t)(r0 + r) * 8);
    float4 d0 = dp[0], d1 = dp[1];
    const float4* hp = (const float4*)(h + (size_t)(r0 + r) * H_N + j0);
    float4 h0 = hp[0], h1 = hp[1];
    float hv[8] = {h0.x, h0.y, h0.z, h0.w, h1.x, h1.y, h1.z, h1.w};
    u16 o[8];
#pragma unroll
    for (int j = 0; j < 8; ++j) {
      float tt = d0.x*w[j][0].x + d0.y*w[j][0].y + d0.z*w[j][0].z + d0.w*w[j][0].w
               + d1.x*w[j][1].x + d1.y*w[j][1].y + d1.z*w[j][1].z + d1.w*w[j][1].w + bgl[j];
      tt = tt > 0.0f ? tt : 0.0f;
      o[j] = f2bf(__expf(-tt) * hv[j]);
    }
    *(float4*)(hdec + (size_t)(r0 + r) * H_N + j0) = *(float4*)o;
  }
}

// ---------- fused GRU GEMM ----------
// Block tile: 128 rows x 64 cols, BK=64 (2 kb-subtiles of 32). 4 waves, wave tile 64x32.
// MFMA 16x16x32. XOR chunk swizzle kills ds_read_b128 bank conflicts:
//   physical 16B chunk = logical chunk ^ ((row>>1)&3)
// Staging honors global_load_lds's contiguous-LDS constraint by permuting the
// GLOBAL source chunk per lane instead of the LDS destination.
__global__ __launch_bounds__(256, 4) void gru_gemm(
    const u16* __restrict__ xb,    // [B, I] bf16
    const u16* __restrict__ hdec,  // [B, H] bf16 (decayed h)
    const u16* __restrict__ wihb,  // [3H, I] bf16
    const u16* __restrict__ whhb,  // [3H, H] bf16
    const float* __restrict__ bih, // [3H]
    const float* __restrict__ bhh, // [3H]
    float* __restrict__ out)       // [B, H] f32
{
  __shared__ __attribute__((aligned(16))) u16 As[2][128 * 32];     // 16 KB
  __shared__ __attribute__((aligned(16))) u16 Ws[3][2][64 * 32];   // 24 KB

  const int tid  = threadIdx.x;
  const int lane = tid & 63;
  const int wave = tid >> 6;
  const int wm = wave & 1;   // row half (64 rows each)
  const int wn = wave >> 1;  // col half (32 cols each)
  const int m0 = blockIdx.x * 128;
  const int j0 = blockIdx.y * 64;

  const int srow = tid >> 2;                              // 0..63 staging row
  const int sk   = (((tid & 3) ^ ((tid >> 3) & 3)) * 8);  // swizzled global chunk
  const int frow = lane & 15;                             // fragment row/col
  const int fkp  = (((lane >> 4) ^ ((frow >> 1) & 3)) * 8); // swizzled read offset

  f32x4 acc[3][4][2];
  u32 park[3][4][2][2];

#pragma unroll
  for (int g = 0; g < 3; ++g)
#pragma unroll
    for (int rb = 0; rb < 4; ++rb)
#pragma unroll
      for (int cb = 0; cb < 2; ++cb)
#pragma unroll
        for (int r = 0; r < 4; ++r) acc[g][rb][cb][r] = 0.0f;

#define GEMM_PASS(APTR, WPTR, LD, KTOT, GBASE)                                  \
  for (int k0 = 0; k0 < (KTOT); k0 += 64) {                                     \
    _Pragma("unroll")                                                           \
    for (int kb = 0; kb < 2; ++kb) {                                            \
      _Pragma("unroll")                                                         \
      for (int o = 0; o < 2; ++o)                                               \
        gld_lds16((APTR) + (size_t)(m0 + o * 64 + srow) * (LD) + k0 + kb * 32 + sk, \
                  &As[kb][o * 2048 + tid * 8]);                                 \
      _Pragma("unroll")                                                         \
      for (int g = 0; g < 3; ++g)                                               \
        gld_lds16((WPTR) + (size_t)(g * H_N + j0 + srow) * (LD) + k0 + kb * 32 + sk, \
                  &Ws[g][kb][tid * 8]);                                         \
    }                                                                           \
    __syncthreads();                                                            \
    _Pragma("unroll")                                                           \
    for (int kb = 0; kb < 2; ++kb) {                                            \
      bf16x8 af[4];                                                             \
      _Pragma("unroll")                                                         \
      for (int rb = 0; rb < 4; ++rb)                                            \
        af[rb] = *(const bf16x8*)&As[kb][(wm * 64 + rb * 16 + frow) * 32 + fkp]; \
      _Pragma("unroll")                                                         \
      for (int g = 0; g < 3; ++g) {                                             \
        _Pragma("unroll")                                                       \
        for (int cb = 0; cb < 2; ++cb) {                                        \
          bf16x8 wf = *(const bf16x8*)&Ws[g][kb][(wn * 32 + cb * 16 + frow) * 32 + fkp]; \
          _Pragma("unroll")                                                     \
          for (int rb = 0; rb < 4; ++rb)                                        \
            acc[(GBASE) + g][rb][cb] = __builtin_amdgcn_mfma_f32_16x16x32_bf16( \
                af[rb], wf, acc[(GBASE) + g][rb][cb], 0, 0, 0);                 \
        }                                                                       \
      }                                                                         \
    }                                                                           \
    __syncthreads();                                                            \
  }

  // ---- K-loop 1: x @ Wih^T (K = 512) ----
  GEMM_PASS(xb, wihb, I_N, I_N, 0)

  // park ih gates as packed bf16, re-zero accs
#pragma unroll
  for (int g = 0; g < 3; ++g)
#pragma unroll
    for (int rb = 0; rb < 4; ++rb)
#pragma unroll
      for (int cb = 0; cb < 2; ++cb) {
        park[g][rb][cb][0] = pack2bf(acc[g][rb][cb][0], acc[g][rb][cb][1]);
        park[g][rb][cb][1] = pack2bf(acc[g][rb][cb][2], acc[g][rb][cb][3]);
#pragma unroll
        for (int r = 0; r < 4; ++r) acc[g][rb][cb][r] = 0.0f;
      }

  // ---- K-loop 2: hdec @ Whh^T (K = 1024) ----
  GEMM_PASS(hdec, whhb, H_N, H_N, 0)

#undef GEMM_PASS

  // ---- epilogue: gates + output ----
  // C/D 16x16: col = lane&15, row = (lane>>4)*4 + reg
#pragma unroll
  for (int cb = 0; cb < 2; ++cb) {
    const int col = j0 + wn * 32 + cb * 16 + frow;
    const float b_ir = bih[col];
    const float b_iz = bih[H_N + col];
    const float b_in = bih[2 * H_N + col];
    const float b_hr = bhh[col];
    const float b_hz = bhh[H_N + col];
    const float b_hn = bhh[2 * H_N + col];
#pragma unroll
    for (int rb = 0; rb < 4; ++rb) {
      const int rbase = m0 + wm * 64 + rb * 16 + (lane >> 4) * 4;
#pragma unroll
      for (int r = 0; r < 4; ++r) {
        const int row = rbase + r;
        const int sh = (r & 1) * 16;
        float ir  = bf2f((u16)(park[0][rb][cb][r >> 1] >> sh)) + b_ir;
        float iz  = bf2f((u16)(park[1][rb][cb][r >> 1] >> sh)) + b_iz;
        float in_ = bf2f((u16)(park[2][rb][cb][r >> 1] >> sh)) + b_in;
        float hr = acc[0][rb][cb][r] + b_hr;
        float hz = acc[1][rb][cb][r] + b_hz;
        float hn = acc[2][rb][cb][r] + b_hn;
        float rg = 1.0f / (1.0f + __expf(-(ir + hr)));
        float zg = 1.0f / (1.0f + __expf(-(iz + hz)));
        float s  = in_ + rg * hn;
        float e  = __expf(2.0f * s);
        float ng = (e - 1.0f) / (e + 1.0f);   // tanh(s), stable both tails
        float hv = bf2f(hdec[(size_t)row * H_N + col]);
        out[(size_t)row * H_N + col] = ng + zg * (hv - ng);
      }
    }
  }
}

extern "C" void kernel_launch(void* const* d_in, const int* in_sizes, int n_in,
                              void* d_out, int out_size, void* d_ws, size_t ws_size,
                              hipStream_t stream) {
  const float* x     = (const float*)d_in[0];
  const float* delta = (const float*)d_in[1];
  const float* h     = (const float*)d_in[2];
  const float* wih   = (const float*)d_in[3];
  const float* whh   = (const float*)d_in[4];
  const float* bih   = (const float*)d_in[5];
  const float* bhh   = (const float*)d_in[6];
  const float* wg    = (const float*)d_in[7];
  const float* bg    = (const float*)d_in[8];
  float* out = (float*)d_out;

  char* ws = (char*)d_ws;
  u16* xb   = (u16*)(ws);                 // x bf16:   8192*512*2  =  8,388,608 B
  u16* hdec = (u16*)(ws + 8388608);       // hdec bf16:8192*1024*2 = 16,777,216 B
  u16* wihb = (u16*)(ws + 25165824);      // Wih bf16: 3072*512*2  =  3,145,728 B
  u16* whhb = (u16*)(ws + 28311552);      // Whh bf16: 3072*1024*2 =  6,291,456 B

  cvt_all<<<4352, 256, 0, stream>>>(x, wih, whh, xb, wihb, whhb);
  decay_kernel<<<512, 256, 0, stream>>>(h, delta, wg, bg, hdec);
  gru_gemm<<<dim3(B_N / 128, H_N / 64), 256, 0, stream>>>(xb, hdec, wihb, whhb, bih, bhh, out);
}

// Round 4
// 228.623 us; speedup vs baseline: 2.2714x; 2.2714x over previous
//
#include <hip/hip_runtime.h>
#include <hip/hip_bf16.h>
#include <stdint.h>

// Problem constants (B=8192, I=512, H=1024, D=8)
#define B_N 8192
#define I_N 512
#define H_N 1024

typedef __bf16 bf16x8 __attribute__((ext_vector_type(8)));
typedef float f32x4 __attribute__((ext_vector_type(4)));
typedef unsigned short u16;
typedef unsigned int u32;

__device__ inline void gld_lds16(const void* g, void* l) {
  __builtin_amdgcn_global_load_lds(
      (const __attribute__((address_space(1))) unsigned int*)g,
      (__attribute__((address_space(3))) unsigned int*)l,
      16, 0, 0);
}

__device__ inline u16 f2bf(float f) {
  __hip_bfloat16 h = __float2bfloat16(f);
  return __builtin_bit_cast(u16, h);
}

__device__ inline float bf2f(u16 b) {
  unsigned int u = ((unsigned int)b) << 16;
  return __builtin_bit_cast(float, u);
}

__device__ inline u32 pack2bf(float lo, float hi) {
  return (u32)f2bf(lo) | ((u32)f2bf(hi) << 16);
}

// ---------- fused f32 -> bf16 conversion for x, Wih, Whh (one launch) ----------
__global__ void cvt_all(const float* __restrict__ x, const float* __restrict__ wih,
                        const float* __restrict__ whh,
                        u16* __restrict__ xb, u16* __restrict__ wihb, u16* __restrict__ whhb) {
  int b = blockIdx.x;
  const float* src; u16* dst; int base;
  if (b < 2048)      { src = x;   dst = xb;   base = b; }
  else if (b < 2816) { src = wih; dst = wihb; base = b - 2048; }
  else               { src = whh; dst = whhb; base = b - 2816; }
  int i = (base * 256 + (int)threadIdx.x) * 8;
  float4 a0 = *(const float4*)(src + i);
  float4 a1 = *(const float4*)(src + i + 4);
  union { u16 u[8]; float4 v; } pk;
  pk.u[0] = f2bf(a0.x); pk.u[1] = f2bf(a0.y); pk.u[2] = f2bf(a0.z); pk.u[3] = f2bf(a0.w);
  pk.u[4] = f2bf(a1.x); pk.u[5] = f2bf(a1.y); pk.u[6] = f2bf(a1.z); pk.u[7] = f2bf(a1.w);
  *(float4*)(dst + i) = pk.v;
}

// ---------- hidden-state decay: hdec = exp(-relu(delta @ Wg^T + bg)) * h ----------
// R1 version (per-element, low register pressure). R2's 8x8-tile version spilled.
__global__ void decay_kernel(const float* __restrict__ h, const float* __restrict__ delta,
                             const float* __restrict__ wg, const float* __restrict__ bg,
                             u16* __restrict__ hdec) {
  int idx = blockIdx.x * 256 + threadIdx.x;   // over B*H
  int b = idx >> 10;        // H_N = 1024
  int j = idx & 1023;
  const float4* d4 = (const float4*)(delta + (size_t)b * 8);
  float4 d0 = d4[0], d1 = d4[1];
  const float4* w4 = (const float4*)(wg + (size_t)j * 8);
  float4 w0 = w4[0], w1 = w4[1];
  float t = d0.x*w0.x + d0.y*w0.y + d0.z*w0.z + d0.w*w0.w
          + d1.x*w1.x + d1.y*w1.y + d1.z*w1.z + d1.w*w1.w + bg[j];
  t = t > 0.0f ? t : 0.0f;
  float gam = __expf(-t);
  hdec[idx] = f2bf(gam * h[idx]);
}

// ---------- fused GRU GEMM ----------
// Block tile: 128 rows x 64 cols, BK=64 (2 kb-subtiles of 32). 4 waves, wave tile 64x32.
// MFMA 16x16x32. XOR chunk swizzle (verified R2: conflicts -> 0):
//   physical 16B chunk = logical chunk ^ ((row>>1)&3)
// Staging permutes the GLOBAL source chunk per lane (LDS dst stays contiguous,
// honoring global_load_lds's wave-uniform-base constraint).
// __launch_bounds__(256,2): (256,4) made the allocator cap regs -> 96-VGPR acc
// spilled to scratch (R2: hbm_bytes 130->795 MB). Compiler picks 128 VGPR here,
// which already yields 4 waves/SIMD without a forced cap.
__global__ __launch_bounds__(256, 2) void gru_gemm(
    const u16* __restrict__ xb,    // [B, I] bf16
    const u16* __restrict__ hdec,  // [B, H] bf16 (decayed h)
    const u16* __restrict__ wihb,  // [3H, I] bf16
    const u16* __restrict__ whhb,  // [3H, H] bf16
    const float* __restrict__ bih, // [3H]
    const float* __restrict__ bhh, // [3H]
    float* __restrict__ out)       // [B, H] f32
{
  __shared__ __attribute__((aligned(16))) u16 As[2][128 * 32];     // 16 KB
  __shared__ __attribute__((aligned(16))) u16 Ws[3][2][64 * 32];   // 24 KB

  const int tid  = threadIdx.x;
  const int lane = tid & 63;
  const int wave = tid >> 6;
  const int wm = wave & 1;   // row half (64 rows each)
  const int wn = wave >> 1;  // col half (32 cols each)
  const int m0 = blockIdx.x * 128;
  const int j0 = blockIdx.y * 64;

  const int srow = tid >> 2;                              // 0..63 staging row
  const int sk   = (((tid & 3) ^ ((tid >> 3) & 3)) * 8);  // swizzled global chunk
  const int frow = lane & 15;                             // fragment row/col
  const int fkp  = (((lane >> 4) ^ ((frow >> 1) & 3)) * 8); // swizzled read offset

  f32x4 acc[3][4][2];
  u32 park[3][4][2][2];

#pragma unroll
  for (int g = 0; g < 3; ++g)
#pragma unroll
    for (int rb = 0; rb < 4; ++rb)
#pragma unroll
      for (int cb = 0; cb < 2; ++cb)
#pragma unroll
        for (int r = 0; r < 4; ++r) acc[g][rb][cb][r] = 0.0f;

#define GEMM_PASS(APTR, WPTR, LD, KTOT)                                         \
  for (int k0 = 0; k0 < (KTOT); k0 += 64) {                                     \
    _Pragma("unroll")                                                           \
    for (int kb = 0; kb < 2; ++kb) {                                            \
      _Pragma("unroll")                                                         \
      for (int o = 0; o < 2; ++o)                                               \
        gld_lds16((APTR) + (size_t)(m0 + o * 64 + srow) * (LD) + k0 + kb * 32 + sk, \
                  &As[kb][o * 2048 + tid * 8]);                                 \
      _Pragma("unroll")                                                         \
      for (int g = 0; g < 3; ++g)                                               \
        gld_lds16((WPTR) + (size_t)(g * H_N + j0 + srow) * (LD) + k0 + kb * 32 + sk, \
                  &Ws[g][kb][tid * 8]);                                         \
    }                                                                           \
    __syncthreads();                                                            \
    _Pragma("unroll")                                                           \
    for (int kb = 0; kb < 2; ++kb) {                                            \
      bf16x8 af[4];                                                             \
      _Pragma("unroll")                                                         \
      for (int rb = 0; rb < 4; ++rb)                                            \
        af[rb] = *(const bf16x8*)&As[kb][(wm * 64 + rb * 16 + frow) * 32 + fkp]; \
      _Pragma("unroll")                                                         \
      for (int g = 0; g < 3; ++g) {                                             \
        _Pragma("unroll")                                                       \
        for (int cb = 0; cb < 2; ++cb) {                                        \
          bf16x8 wf = *(const bf16x8*)&Ws[g][kb][(wn * 32 + cb * 16 + frow) * 32 + fkp]; \
          _Pragma("unroll")                                                     \
          for (int rb = 0; rb < 4; ++rb)                                        \
            acc[g][rb][cb] = __builtin_amdgcn_mfma_f32_16x16x32_bf16(           \
                af[rb], wf, acc[g][rb][cb], 0, 0, 0);                           \
        }                                                                       \
      }                                                                         \
    }                                                                           \
    __syncthreads();                                                            \
  }

  // ---- K-loop 1: x @ Wih^T (K = 512) ----
  GEMM_PASS(xb, wihb, I_N, I_N)

  // park ih gates as packed bf16, re-zero accs
#pragma unroll
  for (int g = 0; g < 3; ++g)
#pragma unroll
    for (int rb = 0; rb < 4; ++rb)
#pragma unroll
      for (int cb = 0; cb < 2; ++cb) {
        park[g][rb][cb][0] = pack2bf(acc[g][rb][cb][0], acc[g][rb][cb][1]);
        park[g][rb][cb][1] = pack2bf(acc[g][rb][cb][2], acc[g][rb][cb][3]);
#pragma unroll
        for (int r = 0; r < 4; ++r) acc[g][rb][cb][r] = 0.0f;
      }

  // ---- K-loop 2: hdec @ Whh^T (K = 1024) ----
  GEMM_PASS(hdec, whhb, H_N, H_N)

#undef GEMM_PASS

  // ---- epilogue: gates + output ----
  // C/D 16x16: col = lane&15, row = (lane>>4)*4 + reg
#pragma unroll
  for (int cb = 0; cb < 2; ++cb) {
    const int col = j0 + wn * 32 + cb * 16 + frow;
    const float b_ir = bih[col];
    const float b_iz = bih[H_N + col];
    const float b_in = bih[2 * H_N + col];
    const float b_hr = bhh[col];
    const float b_hz = bhh[H_N + col];
    const float b_hn = bhh[2 * H_N + col];
#pragma unroll
    for (int rb = 0; rb < 4; ++rb) {
      const int rbase = m0 + wm * 64 + rb * 16 + (lane >> 4) * 4;
#pragma unroll
      for (int r = 0; r < 4; ++r) {
        const int row = rbase + r;
        const int sh = (r & 1) * 16;
        float ir  = bf2f((u16)(park[0][rb][cb][r >> 1] >> sh)) + b_ir;
        float iz  = bf2f((u16)(park[1][rb][cb][r >> 1] >> sh)) + b_iz;
        float in_ = bf2f((u16)(park[2][rb][cb][r >> 1] >> sh)) + b_in;
        float hr = acc[0][rb][cb][r] + b_hr;
        float hz = acc[1][rb][cb][r] + b_hz;
        float hn = acc[2][rb][cb][r] + b_hn;
        float rg = 1.0f / (1.0f + __expf(-(ir + hr)));
        float zg = 1.0f / (1.0f + __expf(-(iz + hz)));
        float s  = in_ + rg * hn;
        float e  = __expf(2.0f * s);
        float ng = (e - 1.0f) / (e + 1.0f);   // tanh(s), stable both tails
        float hv = bf2f(hdec[(size_t)row * H_N + col]);
        out[(size_t)row * H_N + col] = ng + zg * (hv - ng);
      }
    }
  }
}

extern "C" void kernel_launch(void* const* d_in, const int* in_sizes, int n_in,
                              void* d_out, int out_size, void* d_ws, size_t ws_size,
                              hipStream_t stream) {
  const float* x     = (const float*)d_in[0];
  const float* delta = (const float*)d_in[1];
  const float* h     = (const float*)d_in[2];
  const float* wih   = (const float*)d_in[3];
  const float* whh   = (const float*)d_in[4];
  const float* bih   = (const float*)d_in[5];
  const float* bhh   = (const float*)d_in[6];
  const float* wg    = (const float*)d_in[7];
  const float* bg    = (const float*)d_in[8];
  float* out = (float*)d_out;

  char* ws = (char*)d_ws;
  u16* xb   = (u16*)(ws);                 // x bf16:   8192*512*2  =  8,388,608 B
  u16* hdec = (u16*)(ws + 8388608);       // hdec bf16:8192*1024*2 = 16,777,216 B
  u16* wihb = (u16*)(ws + 25165824);      // Wih bf16: 3072*512*2  =  3,145,728 B
  u16* whhb = (u16*)(ws + 28311552);      // Whh bf16: 3072*1024*2 =  6,291,456 B

  cvt_all<<<4352, 256, 0, stream>>>(x, wih, whh, xb, wihb, whhb);
  decay_kernel<<<B_N * H_N / 256, 256, 0, stream>>>(h, delta, wg, bg, hdec);
  gru_gemm<<<dim3(B_N / 128, H_N / 64), 256, 0, stream>>>(xb, hdec, wihb, whhb, bih, bhh, out);
}